// Round 9
// baseline (351.901 us; speedup 1.0000x reference)
//
#include <hip/hip_runtime.h>

// ---------------------------------------------------------------------------
// TransformerBlock: x:[2,2048,1024] fp32
//   qkv = x @ w_qkv;  attention (scale 1/sqrt(1024));  x = x + LN(attn_out)
//   ff  = relu(x@w1+b1)@w2+b2;  out = x + LN(ff)
// R9: fix R8 compile error (Qs declared as pointer-to-[128][32]; index as
//     Qs[h][row][col], not (*Qs)[h][row][col]). Functionally identical plan:
//     (a) c2 prescale folded into w_qkv Q-cols; Q staged via global_load_lds;
//     (b) qkv GEMM epilogue writes vT directly (transpose_v deleted);
//     (c) attn O-partials bf16. GEMM BK=64 + XCD swizzle from R7.
// ---------------------------------------------------------------------------

typedef unsigned short u16;
typedef unsigned int u32;
typedef __bf16 bf16x8 __attribute__((ext_vector_type(8)));
typedef float f32x4 __attribute__((ext_vector_type(4)));
typedef u32 u32x4 __attribute__((ext_vector_type(4)));
typedef u16 u16x4 __attribute__((ext_vector_type(4)));

__device__ __forceinline__ u16 f2b(float f) {
  u32 u = __builtin_bit_cast(u32, f);
  u += 0x7fffu + ((u >> 16) & 1u);       // RNE
  return (u16)(u >> 16);
}
__device__ __forceinline__ float b2f(u16 u) {
  return __builtin_bit_cast(float, (u32)u << 16);
}

// async global->LDS DMA, 16B per lane. LDS dest = wave-uniform base + lane*16.
__device__ __forceinline__ void gld_lds16(const u16* g, u16* l) {
  __builtin_amdgcn_global_load_lds(
      (const __attribute__((address_space(1))) u32*)g,
      (__attribute__((address_space(3))) u32*)l, 16, 0, 0);
}

// ---------------------------------------------------------------------------
__global__ __launch_bounds__(256) void convert_bf16_kernel(
    const float* __restrict__ in, u16* __restrict__ out) {
  const int idx = blockIdx.x * 256 + threadIdx.x;
  float4 v = ((const float4*)in)[idx];
  u16x4 o = { f2b(v.x), f2b(v.y), f2b(v.z), f2b(v.w) };
  ((u16x4*)out)[idx] = o;
}

// fp32[R][C] -> bf16 out[C][R]; output rows n < scale_cols scaled by `scale`
__global__ __launch_bounds__(256) void transpose_bf16_kernel(
    const float* __restrict__ in, u16* __restrict__ out, int R, int C,
    int scale_cols, float scale) {
  __shared__ float tile[32][33];
  const int cb = blockIdx.x * 32, rb = blockIdx.y * 32;
  const int c = threadIdx.x & 31;
  const int r0 = threadIdx.x >> 5;
#pragma unroll
  for (int rr = 0; rr < 32; rr += 8)
    tile[r0 + rr][c] = in[(size_t)(rb + r0 + rr) * C + cb + c];
  __syncthreads();
#pragma unroll
  for (int rr = 0; rr < 32; rr += 8) {
    const int n = cb + r0 + rr;
    const float sc = (n < scale_cols) ? scale : 1.f;
    out[(size_t)n * R + rb + c] = f2b(tile[c][r0 + rr] * sc);
  }
}

// ---------------------------------------------------------------------------
// C[M,N] = A[M,K](bf16) @ Bt[N,K](bf16)^T, fp32 accum. BK=64 (32 MFMA/barrier)
// via half-split LDS [2][128][32]. XCD swizzle (requires M == 32*128).
// Split-K via gridDim.y (bf16 partials Cb/Cb1/Cb2/Cb3).
// If Vt != nullptr, blocks with n0 >= 2048 write transposed V: vt[bh][d][s].
__global__ __launch_bounds__(256) void gemm_bt_kernel(
    const u16* __restrict__ A, const u16* __restrict__ Bt,
    const float* __restrict__ bias, float* __restrict__ Cf, u16* __restrict__ Cb,
    int M, int N, int K, int relu,
    u16* __restrict__ Cb1, u16* __restrict__ Cb2, u16* __restrict__ Cb3,
    u16* __restrict__ Vt) {
  // swizzle: xcd owns 4 m-panels; 4 consecutive same-XCD blocks share n-panel
  const int bid = blockIdx.x;
  const int xcd = bid & 7;
  const int g = bid >> 3;
  const int m0 = (xcd * 4 + (g & 3)) * 128;
  const int n0 = (g >> 2) * 128;
  const int z = blockIdx.y;
  const int kn = K / (int)gridDim.y;
  if (z == 1) Cb = Cb1; else if (z == 2) Cb = Cb2; else if (z == 3) Cb = Cb3;
  const int tid = threadIdx.x;
  const int w = tid >> 6, lane = tid & 63, quad = lane >> 4, l16 = lane & 15;
  const int wm = (w & 1) * 64, wn = (w >> 1) * 64;

  __shared__ u16 As[2][128][32];   // half h = K-cols h*32..h*32+31
  __shared__ u16 Bs[2][128][32];

  f32x4 acc[4][4];
#pragma unroll
  for (int i = 0; i < 4; ++i)
#pragma unroll
    for (int j = 0; j < 4; ++j) acc[i][j] = {0.f, 0.f, 0.f, 0.f};

  // DMA map: wave w, lane l -> row w*16 + (l>>2), col (l&3)*8 within a half
  const int srow = w * 16 + (lane >> 2);
  const int scol = (lane & 3) << 3;
  const u16* Ag = A + (size_t)(m0 + srow) * K + scol + (size_t)z * kn;
  const u16* Bg = Bt + (size_t)(n0 + srow) * K + scol + (size_t)z * kn;
  const size_t rstep = (size_t)64 * K;

  for (int k0 = 0; k0 < kn; k0 += 64) {
    __syncthreads();                 // all waves done reading prev tile
    gld_lds16(Ag + k0,              &As[0][w * 16][0]);
    gld_lds16(Ag + k0 + 32,         &As[1][w * 16][0]);
    gld_lds16(Ag + rstep + k0,      &As[0][64 + w * 16][0]);
    gld_lds16(Ag + rstep + k0 + 32, &As[1][64 + w * 16][0]);
    gld_lds16(Bg + k0,              &Bs[0][w * 16][0]);
    gld_lds16(Bg + k0 + 32,         &Bs[1][w * 16][0]);
    gld_lds16(Bg + rstep + k0,      &Bs[0][64 + w * 16][0]);
    gld_lds16(Bg + rstep + k0 + 32, &Bs[1][64 + w * 16][0]);
    __syncthreads();                 // barrier drains vmcnt -> DMA visible

#pragma unroll
    for (int s = 0; s < 2; ++s) {
      bf16x8 af[4], bfr[4];
#pragma unroll
      for (int i = 0; i < 4; ++i)
        af[i] = *(const bf16x8*)&As[s][wm + i * 16 + l16][quad * 8];
#pragma unroll
      for (int j = 0; j < 4; ++j)
        bfr[j] = *(const bf16x8*)&Bs[s][wn + j * 16 + l16][quad * 8];
#pragma unroll
      for (int i = 0; i < 4; ++i)
#pragma unroll
        for (int j = 0; j < 4; ++j)
          acc[i][j] = __builtin_amdgcn_mfma_f32_16x16x32_bf16(af[i], bfr[j], acc[i][j], 0, 0, 0);
    }
  }

  if (Vt && n0 >= 2048) {
    // V-region block: write vt[bh][d][s] transposed, packed 4-row b64 stores
#pragma unroll
    for (int i = 0; i < 4; ++i) {
      const int row = m0 + wm + i * 16 + quad * 4;
      const int b_ = row >> 11, s = row & 2047;
#pragma unroll
      for (int j = 0; j < 4; ++j) {
        const int vcol = n0 + wn + j * 16 + l16 - 2048;
        u16* dst = Vt + ((size_t)((b_ << 4) + (vcol >> 6)) * 64 + (vcol & 63)) * 2048 + s;
        u16x4 o = { f2b(acc[i][j][0]), f2b(acc[i][j][1]),
                    f2b(acc[i][j][2]), f2b(acc[i][j][3]) };
        *(u16x4*)dst = o;
      }
    }
    return;
  }

#pragma unroll
  for (int i = 0; i < 4; ++i) {
    const int row = m0 + wm + i * 16 + quad * 4;
#pragma unroll
    for (int j = 0; j < 4; ++j) {
      const int col = n0 + wn + j * 16 + l16;
      const float bv = bias ? bias[col] : 0.f;
#pragma unroll
      for (int r = 0; r < 4; ++r) {
        float v = acc[i][j][r] + bv;
        if (relu) v = fmaxf(v, 0.f);
        const size_t idx = (size_t)(row + r) * N + col;
        if (Cf) Cf[idx] = v;
        if (Cb) Cb[idx] = f2b(v);
      }
    }
  }
}

// ---------------------------------------------------------------------------
// Flash attention, fixed-max softmax, split over keys (kz in {0,1}).
// Block = (bh, 128 q-rows, 1024-key range); 4 waves x 32 q-rows.
// Q is PRE-SCALED by log2(e)/sqrt(1024) (folded into w_qkv) -> staged via DMA.
// Writes UNNORMALIZED O partial (bf16) + l partial (fp32); LN1 combines.
__global__ __launch_bounds__(256, 4) void attn_kernel(
    const u16* __restrict__ qkv, const u16* __restrict__ vt,
    u16* __restrict__ Op0, u16* __restrict__ Op1,
    float* __restrict__ lpart) {
  const int bh = blockIdx.x;          // b*16 + nh
  const int qt = blockIdx.y;          // 0..15
  const int kz = blockIdx.z;          // 0..1
  const int b = bh >> 4, nh = bh & 15;
  const int tid = threadIdx.x;
  const int w = tid >> 6, lane = tid & 63, quad = lane >> 4, l16 = lane & 15;

  __shared__ u16 KH[2][64][32];       // K tile: half h = dims h*32.., [key][d%32]
  __shared__ u16 VH[2][64][32];       // V^T tile: half kk = keys kk*32.., [d][key%32]
  __shared__ u16 QP[4][32][68];       // per-wave P [q][key]; pre-loop: Q halves
  u16 (*Qs)[128][32] = (u16 (*)[128][32])&QP[0][0][0];  // Qs[h][row][col], 16 KB

  const size_t rs = 3072;
  const u16* qbase = qkv + (size_t)b * 2048 * rs + nh * 64;
  const u16* kbase = qbase + 1024;
  const u16* vbase = vt + (size_t)bh * 64 * 2048;
  const int q0 = qt * 128;
  const int k0beg = kz * 1024;

  const int drow = lane >> 2;         // 0..15
  const int dcol = (lane & 3) << 3;   // 0,8,16,24

  // stage Q (128x64, pre-scaled) via DMA into half-split layout
#pragma unroll
  for (int rr = 0; rr < 128; rr += 64)
#pragma unroll
    for (int h = 0; h < 2; ++h)
      gld_lds16(qbase + (size_t)(q0 + rr + w * 16 + drow) * rs + h * 32 + dcol,
                &Qs[h][rr + w * 16][0]);
  __syncthreads();

  bf16x8 aq[2][2];
#pragma unroll
  for (int mi = 0; mi < 2; ++mi)
#pragma unroll
    for (int d0 = 0; d0 < 2; ++d0)
      aq[mi][d0] = *(const bf16x8*)&Qs[d0][w * 32 + mi * 16 + l16][quad * 8];

  bf16x8 ones;
#pragma unroll
  for (int j = 0; j < 8; ++j) ones[j] = (__bf16)1.0f;

  f32x4 Oacc[2][4], l_acc[2];
#pragma unroll
  for (int mi = 0; mi < 2; ++mi) {
    l_acc[mi] = {0.f, 0.f, 0.f, 0.f};
#pragma unroll
    for (int jt = 0; jt < 4; ++jt) Oacc[mi][jt] = {0.f, 0.f, 0.f, 0.f};
  }

#pragma unroll 1
  for (int t = 0; t < 16; ++t) {
    const int k0 = k0beg + t * 64;
    __syncthreads();                  // all waves done with prev tile (and Qs/aq on t=0)
    gld_lds16(kbase + (size_t)(k0 + w * 16 + drow) * rs + dcol,        &KH[0][w * 16][0]);
    gld_lds16(kbase + (size_t)(k0 + w * 16 + drow) * rs + 32 + dcol,   &KH[1][w * 16][0]);
    gld_lds16(vbase + (size_t)(w * 16 + drow) * 2048 + k0 + dcol,      &VH[0][w * 16][0]);
    gld_lds16(vbase + (size_t)(w * 16 + drow) * 2048 + k0 + 32 + dcol, &VH[1][w * 16][0]);
    __syncthreads();                  // barrier drains vmcnt -> DMA visible

    // S = Q K^T : 16 MFMA, 8 K-frag reads (each feeds both mi)
    f32x4 S[2][4];
#pragma unroll
    for (int mi = 0; mi < 2; ++mi)
#pragma unroll
      for (int jt = 0; jt < 4; ++jt) S[mi][jt] = {0.f, 0.f, 0.f, 0.f};
#pragma unroll
    for (int d0 = 0; d0 < 2; ++d0)
#pragma unroll
      for (int jt = 0; jt < 4; ++jt) {
        bf16x8 bv = *(const bf16x8*)&KH[d0][jt * 16 + l16][quad * 8];
        S[0][jt] = __builtin_amdgcn_mfma_f32_16x16x32_bf16(aq[0][d0], bv, S[0][jt], 0, 0, 0);
        S[1][jt] = __builtin_amdgcn_mfma_f32_16x16x32_bf16(aq[1][d0], bv, S[1][jt], 0, 0, 0);
      }

    // p = exp2(S); truncating bf16 pack (bias cancels in O/l)
#pragma unroll
    for (int mi = 0; mi < 2; ++mi)
#pragma unroll
      for (int jt = 0; jt < 4; ++jt)
#pragma unroll
        for (int r = 0; r < 4; ++r) {
          float p = exp2f(S[mi][jt][r]);
          QP[w][mi * 16 + quad * 4 + r][jt * 16 + l16] =
              (u16)(__builtin_bit_cast(u32, p) >> 16);
        }

    // O += P V ; l += P 1 : 20 MFMA, 8 V-frag + 4 P-frag reads
    bf16x8 ap[2][2];
#pragma unroll
    for (int mi = 0; mi < 2; ++mi)
#pragma unroll
      for (int kk = 0; kk < 2; ++kk)
        ap[mi][kk] = *(const bf16x8*)&QP[w][mi * 16 + l16][kk * 32 + quad * 8];
#pragma unroll
    for (int kk = 0; kk < 2; ++kk) {
#pragma unroll
      for (int jt = 0; jt < 4; ++jt) {
        bf16x8 bv = *(const bf16x8*)&VH[kk][jt * 16 + l16][quad * 8];
        Oacc[0][jt] = __builtin_amdgcn_mfma_f32_16x16x32_bf16(ap[0][kk], bv, Oacc[0][jt], 0, 0, 0);
        Oacc[1][jt] = __builtin_amdgcn_mfma_f32_16x16x32_bf16(ap[1][kk], bv, Oacc[1][jt], 0, 0, 0);
      }
      l_acc[0] = __builtin_amdgcn_mfma_f32_16x16x32_bf16(ap[0][kk], ones, l_acc[0], 0, 0, 0);
      l_acc[1] = __builtin_amdgcn_mfma_f32_16x16x32_bf16(ap[1][kk], ones, l_acc[1], 0, 0, 0);
    }
  }

  u16* opart = kz ? Op1 : Op0;
  u16* obase = opart + (size_t)b * 2048 * 1024 + (size_t)nh * 64;
  float* lbase = lpart + (size_t)kz * 4096 * 16 + (size_t)b * 2048 * 16 + nh;
#pragma unroll
  for (int mi = 0; mi < 2; ++mi) {
    const int qrow = q0 + w * 32 + mi * 16 + quad * 4;
#pragma unroll
    for (int r = 0; r < 4; ++r) {
#pragma unroll
      for (int jt = 0; jt < 4; ++jt)
        obase[(size_t)(qrow + r) * 1024 + jt * 16 + l16] = f2b(Oacc[mi][jt][r]);
      if (l16 == 0) lbase[(size_t)(qrow + r) * 16] = l_acc[mi][r];
    }
  }
}

// ---------------------------------------------------------------------------
// x1 = xres + LN((O0+O1)/(l0+l1))*g + b ; O partials bf16; writes fp32 + bf16
__global__ __launch_bounds__(256) void ln_attn_kernel(
    const u16* __restrict__ O0, const u16* __restrict__ O1,
    const float* __restrict__ l0, const float* __restrict__ l1,
    const float* __restrict__ xres, const float* __restrict__ g,
    const float* __restrict__ bb, float* __restrict__ outf,
    u16* __restrict__ outb) {
  const int row = blockIdx.x;
  const int tid = threadIdx.x;
  const int w = tid >> 6, lane = tid & 63;
  const int head = tid >> 4;
  u16x4 a0 = ((const u16x4*)(O0 + (size_t)row * 1024))[tid];
  u16x4 a1 = ((const u16x4*)(O1 + (size_t)row * 1024))[tid];
  const float inv = 1.f / (l0[row * 16 + head] + l1[row * 16 + head]);
  float4 v;
  v.x = (b2f(a0[0]) + b2f(a1[0])) * inv;
  v.y = (b2f(a0[1]) + b2f(a1[1])) * inv;
  v.z = (b2f(a0[2]) + b2f(a1[2])) * inv;
  v.w = (b2f(a0[3]) + b2f(a1[3])) * inv;
  float s = v.x + v.y + v.z + v.w;
  float s2 = v.x * v.x + v.y * v.y + v.z * v.z + v.w * v.w;
#pragma unroll
  for (int off = 32; off > 0; off >>= 1) {
    s += __shfl_xor(s, off);
    s2 += __shfl_xor(s2, off);
  }
  __shared__ float red[8];
  if (lane == 0) { red[w] = s; red[4 + w] = s2; }
  __syncthreads();
  s = red[0] + red[1] + red[2] + red[3];
  s2 = red[4] + red[5] + red[6] + red[7];
  const float mu = s * (1.f / 1024.f);
  const float var = s2 * (1.f / 1024.f) - mu * mu;
  const float rstd = rsqrtf(var + 1e-5f);
  float4 xr = ((const float4*)(xres + (size_t)row * 1024))[tid];
  float4 gv = ((const float4*)g)[tid];
  float4 bv = ((const float4*)bb)[tid];
  float4 o;
  o.x = xr.x + (v.x - mu) * rstd * gv.x + bv.x;
  o.y = xr.y + (v.y - mu) * rstd * gv.y + bv.y;
  o.z = xr.z + (v.z - mu) * rstd * gv.z + bv.z;
  o.w = xr.w + (v.w - mu) * rstd * gv.w + bv.w;
  ((float4*)(outf + (size_t)row * 1024))[tid] = o;
  u16x4 ob = { f2b(o.x), f2b(o.y), f2b(o.z), f2b(o.w) };
  *(u16x4*)(outb + (size_t)row * 1024 + (size_t)tid * 4) = ob;
}

// ---------------------------------------------------------------------------
// out = xres + LN(p0+p1+p2+p3 + bias)*g + b  (FFN2 split-K combine), fp32 out
__global__ __launch_bounds__(256) void ln_ffn_kernel(
    const u16* __restrict__ p0, const u16* __restrict__ p1,
    const u16* __restrict__ p2, const u16* __restrict__ p3,
    const float* __restrict__ bias, const float* __restrict__ xres,
    const float* __restrict__ g, const float* __restrict__ bb,
    float* __restrict__ outf) {
  const int row = blockIdx.x;
  const int tid = threadIdx.x;
  const int w = tid >> 6, lane = tid & 63;
  u16x4 a0 = ((const u16x4*)(p0 + (size_t)row * 1024))[tid];
  u16x4 a1 = ((const u16x4*)(p1 + (size_t)row * 1024))[tid];
  u16x4 a2 = ((const u16x4*)(p2 + (size_t)row * 1024))[tid];
  u16x4 a3 = ((const u16x4*)(p3 + (size_t)row * 1024))[tid];
  float4 bv4 = ((const float4*)bias)[tid];
  float4 v;
  v.x = (b2f(a0[0]) + b2f(a1[0])) + (b2f(a2[0]) + b2f(a3[0])) + bv4.x;
  v.y = (b2f(a0[1]) + b2f(a1[1])) + (b2f(a2[1]) + b2f(a3[1])) + bv4.y;
  v.z = (b2f(a0[2]) + b2f(a1[2])) + (b2f(a2[2]) + b2f(a3[2])) + bv4.z;
  v.w = (b2f(a0[3]) + b2f(a1[3])) + (b2f(a2[3]) + b2f(a3[3])) + bv4.w;
  float s = v.x + v.y + v.z + v.w;
  float s2 = v.x * v.x + v.y * v.y + v.z * v.z + v.w * v.w;
#pragma unroll
  for (int off = 32; off > 0; off >>= 1) {
    s += __shfl_xor(s, off);
    s2 += __shfl_xor(s2, off);
  }
  __shared__ float red[8];
  if (lane == 0) { red[w] = s; red[4 + w] = s2; }
  __syncthreads();
  s = red[0] + red[1] + red[2] + red[3];
  s2 = red[4] + red[5] + red[6] + red[7];
  const float mu = s * (1.f / 1024.f);
  const float var = s2 * (1.f / 1024.f) - mu * mu;
  const float rstd = rsqrtf(var + 1e-5f);
  float4 xr = ((const float4*)(xres + (size_t)row * 1024))[tid];
  float4 gv = ((const float4*)g)[tid];
  float4 bv = ((const float4*)bb)[tid];
  float4 o;
  o.x = xr.x + (v.x - mu) * rstd * gv.x + bv.x;
  o.y = xr.y + (v.y - mu) * rstd * gv.y + bv.y;
  o.z = xr.z + (v.z - mu) * rstd * gv.z + bv.z;
  o.w = xr.w + (v.w - mu) * rstd * gv.w + bv.w;
  ((float4*)(outf + (size_t)row * 1024))[tid] = o;
}

// ---------------------------------------------------------------------------
extern "C" void kernel_launch(void* const* d_in, const int* in_sizes, int n_in,
                              void* d_out, int out_size, void* d_ws, size_t ws_size,
                              hipStream_t stream) {
  const float* x     = (const float*)d_in[0];
  const float* w_qkv = (const float*)d_in[1];
  const float* ln1_g = (const float*)d_in[2];
  const float* ln1_b = (const float*)d_in[3];
  const float* w1    = (const float*)d_in[4];
  const float* b1    = (const float*)d_in[5];
  const float* w2    = (const float*)d_in[6];
  const float* b2    = (const float*)d_in[7];
  const float* ln2_g = (const float*)d_in[8];
  const float* ln2_b = (const float*)d_in[9];
  float* out = (float*)d_out;
  char* ws = (char*)d_ws;

  const float c2 = 0.04508422f;   // log2(e)/sqrt(1024), folded into w_qkv Q-cols

  // workspace (lifetime-aliased; max end = 98,566,144 B):
  u16*   xb    = (u16*)(ws + 0);              // [0,8.4M)     dead after qkv gemm
  u16*   wqkvT = (u16*)(ws + 8388608);        // [8.4,14.7M)  dead after qkv gemm
  u16*   qkvb  = (u16*)(ws + 31457280);       // [31.5,56.6M) dead after attn
  u16*   vT    = (u16*)(ws + 56623104);       // [56.6,73.4M) dead after attn
  u16*   Op0   = (u16*)(ws + 0);              // [0,8.4M)     attn partial 0 (over dead xb)
  u16*   Op1   = (u16*)(ws + 73400320);       // [73.4,81.8M) attn partial 1
  float* lp    = (float*)(ws + 90177536);     // [90.2,90.7M) l partials (2x256KB)
  float* x1    = (float*)(ws + 31457280);     // [31.5,48.2M) over dead qkvb (after attn)
  u16*   x1b   = (u16*)(ws + 48234496);       // [48.2,56.6M) over dead qkvb; dead after FFN1
  u16*   w1T   = (u16*)(ws + 14680064);       // [14.7,23.1M)
  u16*   w2T   = (u16*)(ws + 23068672);       // [23.1,31.5M)
  u16*   h1    = (u16*)(ws + 56623104);       // [56.6,90.2M) over dead vT+Op1
  u16*   fp0   = (u16*)(ws + 0);              // FFN2 partials (over dead Op0/x1b/lp)
  u16*   fp1   = (u16*)(ws + 8388608);
  u16*   fp2   = (u16*)(ws + 48234496);
  u16*   fp3   = (u16*)(ws + 90177536);

  convert_bf16_kernel<<<4096, 256, 0, stream>>>(x, xb);
  transpose_bf16_kernel<<<dim3(96, 32), 256, 0, stream>>>(w_qkv, wqkvT, 1024, 3072,
                                                          1024, c2);

  // qkv: M=4096 N=3072 K=1024; V-blocks (n0>=2048) write vT directly
  gemm_bt_kernel<<<dim3(32 * 24, 1), 256, 0, stream>>>(
      xb, wqkvT, nullptr, nullptr, qkvb, 4096, 3072, 1024, 0,
      nullptr, nullptr, nullptr, vT);
  attn_kernel<<<dim3(32, 16, 2), 256, 0, stream>>>(qkvb, vT, Op0, Op1, lp);

  ln_attn_kernel<<<4096, 256, 0, stream>>>(
      Op0, Op1, lp, lp + 4096 * 16, x, ln1_g, ln1_b, x1, x1b);

  transpose_bf16_kernel<<<dim3(128, 32), 256, 0, stream>>>(w1, w1T, 1024, 4096, 0, 1.f);
  transpose_bf16_kernel<<<dim3(32, 128), 256, 0, stream>>>(w2, w2T, 4096, 1024, 0, 1.f);

  // FFN1: M=4096 N=4096 K=1024
  gemm_bt_kernel<<<dim3(32 * 32, 1), 256, 0, stream>>>(
      x1b, w1T, b1, nullptr, h1, 4096, 4096, 1024, 1,
      nullptr, nullptr, nullptr, nullptr);
  // FFN2: M=4096 N=1024 K=4096, split-K=4 via gridDim.y
  gemm_bt_kernel<<<dim3(32 * 8, 4), 256, 0, stream>>>(
      h1, w2T, nullptr, nullptr, fp0, 4096, 1024, 4096, 0,
      fp1, fp2, fp3, nullptr);

  ln_ffn_kernel<<<4096, 256, 0, stream>>>(
      fp0, fp1, fp2, fp3, b2, x1, ln2_g, ln2_b, out);
}